// Round 3
// baseline (6309.337 us; speedup 1.0000x reference)
//
#include <hip/hip_runtime.h>
#include <hip/hip_bf16.h>

typedef unsigned short u16;
typedef unsigned int u32;
typedef __attribute__((ext_vector_type(8))) short short8;
typedef __attribute__((ext_vector_type(4))) float floatx4;

#define EPS 0.01f

// ---- workspace layout (bytes) --- total 630784 B (~620 KB) ----
#define OFF_FLAGS  (0ull)         // int  [4][64]            1024 B
#define OFF_HPART  (4096ull)      // fp32 [2][4][16][64]     32768 B
#define OFF_HST    (40960ull)     // bf16 [2][4][16][1024]   262144 B
#define OFF_DHST   (303104ull)    // bf16 [2][4][16][1024]   262144 B
#define OFF_XNORM  (565248ull)    // fp32 [16384]            65536 B

__device__ __forceinline__ u16 f2b(float v) {
  __hip_bfloat16 b = __float2bfloat16(v);
  return *reinterpret_cast<u16*>(&b);
}
__device__ __forceinline__ float b2f(u16 u) {
  u32 x = ((u32)u) << 16;
  return __uint_as_float(x);
}
// extract bf16 half (hi?high:low) of an fp32 word's bit pattern
__device__ __forceinline__ float halfsel(float w, int hi) {
  u32 u = __float_as_uint(w);
  return b2f((u16)(hi ? (u >> 16) : (u & 0xffffu)));
}
__device__ __forceinline__ float sigm(float x) { return 1.0f / (1.0f + __expf(-x)); }
__device__ __forceinline__ float tanh_(float x) { return 2.0f / (1.0f + __expf(-2.0f * x)) - 1.0f; }

// prex chunk addressing: pre-activation (m = t*64+b_glob, col = q*1024 + jt*16 + jj)
// lives as u16 inside d_out at u16 index:
//   (q>=2 ? 33554432 : 0) + m*2048 + jt*32 + (q&1)*16 + jj
// i.e. fp32 out elements [m*1024 + jt*16, +16) of the hs half hold gates 0,1 and the
// same run of the dhs half holds gates 2,3 — exactly the bytes WG (grp=b/16, jt)
// overwrites with final h/dh at step t = m/64 (byte-disjoint across WGs).

// ---------------- xnorm2[t*64+b] = sum_k x[t,b,k]^2 ----------------
__global__ void xnorm_kernel(const float* __restrict__ x, float* __restrict__ xn) {
  const int wid = threadIdx.x >> 6, lane = threadIdx.x & 63;
  const int row = blockIdx.x * 4 + wid;  // 4096 blocks * 4 waves = 16384 rows
  const float4* p = (const float4*)(x + (size_t)row * 1024);
  float s = 0.f;
  #pragma unroll
  for (int i = 0; i < 4; ++i) {
    float4 v = p[lane + i * 64];
    s += v.x * v.x + v.y * v.y + v.z * v.z + v.w * v.w;
  }
  for (int o = 32; o; o >>= 1) s += __shfl_down(s, o);
  if (lane == 0) xn[row] = s;
}

// ------- prex = x @ W_ih^T + (b_ih+b_hh), fp32 in, bf16 chunks into d_out -------
// M=16384 N=4096 K=1024; 128x128 tile, BK=64. fp32->bf16 conversion fused in staging.
#define LDA 88
__global__ __launch_bounds__(256) void pregemm_kernel(const float* __restrict__ A,
                                                      const float* __restrict__ Bw,
                                                      const float* __restrict__ bih,
                                                      const float* __restrict__ bhh,
                                                      u16* __restrict__ O) {
  __shared__ u16 Al[128 * LDA];
  __shared__ u16 Bl[128 * LDA];
  const int tid = threadIdx.x, lane = tid & 63, wid = tid >> 6;
  const int bm = blockIdx.x & 127, bn = blockIdx.x >> 7;
  const size_t m0 = (size_t)bm * 128, n0 = (size_t)bn * 128;
  const int wrow = (wid & 1) * 64, wcol = (wid >> 1) * 64;
  const int lrow = lane & 15, lko = (lane >> 4) * 8;
  floatx4 acc[4][4];
  #pragma unroll
  for (int i = 0; i < 4; ++i)
    #pragma unroll
    for (int j = 0; j < 4; ++j) acc[i][j] = (floatx4)(0.0f);

  for (int k0 = 0; k0 < 1024; k0 += 64) {
    __syncthreads();
    // stage full 128x64 tiles: 2048 float4 chunks per buffer, 8 iters x 256 thr
    #pragma unroll
    for (int i = 0; i < 8; ++i) {
      int cid = tid + i * 256;       // 0..2047
      int row = cid >> 4;            // 0..127  (FULL tile now)
      int kc = cid & 15;             // 16 chunks of 4 elems = 64 k
      float4 va = *(const float4*)&A[(m0 + row) * 1024 + k0 + kc * 4];
      ushort4 oa;
      oa.x = f2b(va.x); oa.y = f2b(va.y); oa.z = f2b(va.z); oa.w = f2b(va.w);
      *(ushort4*)&Al[row * LDA + kc * 4] = oa;
      float4 vb = *(const float4*)&Bw[(n0 + row) * 1024 + k0 + kc * 4];
      ushort4 ob;
      ob.x = f2b(vb.x); ob.y = f2b(vb.y); ob.z = f2b(vb.z); ob.w = f2b(vb.w);
      *(ushort4*)&Bl[row * LDA + kc * 4] = ob;
    }
    __syncthreads();
    #pragma unroll
    for (int ks = 0; ks < 2; ++ks) {
      short8 af[4], bf[4];
      #pragma unroll
      for (int i = 0; i < 4; ++i)
        af[i] = *(const short8*)&Al[(wrow + i * 16 + lrow) * LDA + ks * 32 + lko];
      #pragma unroll
      for (int j = 0; j < 4; ++j)
        bf[j] = *(const short8*)&Bl[(wcol + j * 16 + lrow) * LDA + ks * 32 + lko];
      #pragma unroll
      for (int i = 0; i < 4; ++i)
        #pragma unroll
        for (int j = 0; j < 4; ++j)
          acc[i][j] = __builtin_amdgcn_mfma_f32_16x16x32_bf16(af[i], bf[j], acc[i][j], 0, 0, 0);
    }
  }
  #pragma unroll
  for (int j = 0; j < 4; ++j) {
    const size_t col = n0 + wcol + j * 16 + lrow;
    const float bv = bih[col] + bhh[col];
    const size_t q = col >> 10;
    const size_t jt = (col & 1023) >> 4;
    const size_t jj = col & 15;
    const size_t cbase = ((q >= 2) ? 33554432ull : 0ull) + jt * 32 + (q & 1) * 16 + jj;
    #pragma unroll
    for (int i = 0; i < 4; ++i) {
      const size_t rowb = m0 + wrow + i * 16 + (lane >> 4) * 4;
      #pragma unroll
      for (int r = 0; r < 4; ++r) O[cbase + (rowb + r) * 2048] = f2b(acc[i][j][r] + bv);
    }
  }
}

// ---------------- persistent recurrent kernel ----------------
// 256 WGs x 256 thr, 1 WG/CU (LDS 148992 B). grp = blk&3 owns 16 batch rows,
// jt = blk>>2 owns 16 j-cols across all 4 gates. W_hh slice LDS-resident
// (converted fp32->bf16 at load). Per-step dataflow sync: flags[grp][jt] = t+1
// (release/agent); consumers poll all 64 jt flags of their grp (0xAA poison is
// negative as signed int -> "not ready"; works without zero-init).
__global__ __launch_bounds__(256, 1) void recurrent_kernel(
    const float* __restrict__ gin, const float* __restrict__ whh,
    const float* __restrict__ xnorm2, u16* h_state, u16* dh_state,
    float* hpart, int* flags, float* out) {
  extern __shared__ char smem[];
  u16* Wlds = (u16*)smem;                // [64][1032]  132096 B
  u16* Ast = (u16*)(smem + 132096);      // [32][264]    16896 B (aliased w/ red bufs)
  float* red0 = (float*)(smem + 132096); // 8192 B
  float* red1 = red0 + 2048;             // 8192 B

  const int tid = threadIdx.x, lane = tid & 63, wid = tid >> 6;
  const int grp = blockIdx.x & 3, jt = blockIdx.x >> 2;
  const int lrow = lane & 15, lko = (lane >> 4) * 8;

  // W_hh slice: LDS row q*16+jj <- global row q*1024 + jt*16 + jj (fp32 -> bf16)
  #pragma unroll
  for (int it = 0; it < 64; ++it) {
    int cid = tid + it * 256;        // 0..16383
    int rowl = cid >> 8;             // 0..63
    int kc = cid & 255;              // 256 chunks of 4 = 1024 k
    int q = rowl >> 4, jj = rowl & 15;
    size_t grow = (size_t)q * 1024 + (size_t)jt * 16 + jj;
    float4 v = *(const float4*)&whh[grow * 1024 + kc * 4];
    ushort4 o;
    o.x = f2b(v.x); o.y = f2b(v.y); o.z = f2b(v.z); o.w = f2b(v.w);
    *(ushort4*)&Wlds[rowl * 1032 + kc * 4] = o;
  }
  __syncthreads();

  float cr[4] = {0.f, 0.f, 0.f, 0.f}, dcr[4] = {0.f, 0.f, 0.f, 0.f};

  for (int t = 0; t < 256; ++t) {
    const int p = t & 1, p2 = p ^ 1;
    floatx4 acc[2][4];
    #pragma unroll
    for (int m = 0; m < 2; ++m)
      #pragma unroll
      for (int q = 0; q < 4; ++q) acc[m][q] = (floatx4)(0.0f);

    if (t > 0) {
      if (wid == 0) {
        for (int it = 0; it < 2000000; ++it) {
          int v = __hip_atomic_load(&flags[grp * 64 + lane], __ATOMIC_RELAXED,
                                    __HIP_MEMORY_SCOPE_AGENT);
          if (__all(v >= t)) break;
          __builtin_amdgcn_s_sleep(2);
        }
      }
      __syncthreads();
      __builtin_amdgcn_fence(__ATOMIC_ACQUIRE, "agent");

      const u16* hsrc = h_state + ((size_t)(p * 4 + grp)) * 16 * 1024;
      const u16* dsrc = dh_state + ((size_t)(p * 4 + grp)) * 16 * 1024;
      for (int c = 0; c < 4; ++c) {  // K chunks of 256
        __syncthreads();
        #pragma unroll
        for (int i = 0; i < 4; ++i) {
          int cid = tid + i * 256;   // 1024 chunks of 8 u16
          int rowl = cid >> 5, kc = cid & 31;
          const u16* src = (rowl < 16) ? (hsrc + (size_t)rowl * 1024)
                                       : (dsrc + (size_t)(rowl - 16) * 1024);
          *(ushort4*)&Ast[rowl * 264 + kc * 8] = *(const ushort4*)&src[c * 256 + kc * 8];
          *(ushort4*)&Ast[rowl * 264 + kc * 8 + 4] = *(const ushort4*)&src[c * 256 + kc * 8 + 4];
        }
        __syncthreads();
        const int kq = wid * 64;  // wave's K quarter
        #pragma unroll
        for (int ks = 0; ks < 2; ++ks) {
          const int kl = kq + ks * 32;
          const int kg = c * 256 + kl;
          short8 a0 = *(const short8*)&Ast[lrow * 264 + kl + lko];
          short8 a1 = *(const short8*)&Ast[(16 + lrow) * 264 + kl + lko];
          #pragma unroll
          for (int q = 0; q < 4; ++q) {
            short8 bq = *(const short8*)&Wlds[(q * 16 + lrow) * 1032 + kg + lko];
            acc[0][q] = __builtin_amdgcn_mfma_f32_16x16x32_bf16(a0, bq, acc[0][q], 0, 0, 0);
            acc[1][q] = __builtin_amdgcn_mfma_f32_16x16x32_bf16(a1, bq, acc[1][q], 0, 0, 0);
          }
        }
      }
      // cross-wave K reduction
      __syncthreads();
      if (wid == 1 || wid == 3) {
        float* buf = (wid == 1) ? red0 : red1;
        #pragma unroll
        for (int m = 0; m < 2; ++m)
          #pragma unroll
          for (int q = 0; q < 4; ++q)
            *(floatx4*)&buf[((m * 4 + q) * 64 + lane) * 4] = acc[m][q];
      }
      __syncthreads();
      if (wid == 0 || wid == 2) {
        float* buf = (wid == 0) ? red0 : red1;
        #pragma unroll
        for (int m = 0; m < 2; ++m)
          #pragma unroll
          for (int q = 0; q < 4; ++q)
            acc[m][q] += *(floatx4*)&buf[((m * 4 + q) * 64 + lane) * 4];
      }
      __syncthreads();
      if (wid == 2) {
        #pragma unroll
        for (int m = 0; m < 2; ++m)
          #pragma unroll
          for (int q = 0; q < 4; ++q)
            *(floatx4*)&red0[((m * 4 + q) * 64 + lane) * 4] = acc[m][q];
      }
      __syncthreads();
      if (wid == 0) {
        #pragma unroll
        for (int m = 0; m < 2; ++m)
          #pragma unroll
          for (int q = 0; q < 4; ++q)
            acc[m][q] += *(floatx4*)&red0[((m * 4 + q) * 64 + lane) * 4];
      }
    }

    if (wid == 0) {
      // ---- epilogue: lane -> col j=jt*16+(lane&15), rows b=(lane>>4)*4+r ----
      const int jcol = lane & 15;
      const int j = jt * 16 + jcol;
      const int bb = (lane >> 4) * 4;
      float hnq = 0.f;
      if (t > 0) {
        const int b_l = lane >> 2, seg = lane & 3;
        const float* hp = hpart + ((size_t)(p * 4 + grp) * 16 + b_l) * 64 + seg * 16;
        float s = 0.f;
        #pragma unroll
        for (int u = 0; u < 4; ++u) {
          float4 v = *(const float4*)(hp + u * 4);
          s += v.x + v.y + v.z + v.w;
        }
        s += __shfl_xor(s, 1);
        s += __shfl_xor(s, 2);
        hnq = s;
      }
      // Load ALL prex chunks (as float words of `out` -> reorder-safe vs float
      // stores below) + g values BEFORE any out store.
      const int hi = jcol & 1;
      float pre[4][4], gvv[4][4];
      #pragma unroll
      for (int r = 0; r < 4; ++r) {
        const size_t m = (size_t)t * 64 + grp * 16 + bb + r;
        const size_t fb = m * 1024 + (size_t)jt * 16 + (jcol >> 1);
        pre[r][0] = halfsel(out[fb], hi);
        pre[r][1] = halfsel(out[fb + 8], hi);
        pre[r][2] = halfsel(out[16777216ull + fb], hi);
        pre[r][3] = halfsel(out[16777216ull + fb + 8], hi);
        #pragma unroll
        for (int q = 0; q < 4; ++q)
          gvv[r][q] = EPS * gin[m * 4096 + (size_t)q * 1024 + j];
      }
      asm volatile("" ::: "memory");  // loads above may not cross stores below
      #pragma unroll
      for (int r = 0; r < 4; ++r) {
        const int b = bb + r;
        const size_t row = (size_t)t * 64 + grp * 16 + b;
        float hn = (t > 0) ? __shfl(hnq, b << 2) : 0.f;
        float sum2 = xnorm2[row] + hn;
        float nrm = sqrtf(sum2 + 2.0f);
        float inv = 1.0f / nrm;
        float s_ = sum2 * inv;
        float pv[4], dpr[4];
        #pragma unroll
        for (int q = 0; q < 4; ++q) {
          pv[q] = acc[0][q][r] + pre[r][q];
          dpr[q] = acc[1][q][r];
        }
        float d0 = gvv[r][0] * (s_ + inv) + gvv[r][1] * inv + dpr[0];
        float d1 = gvv[r][1] * s_ + (gvv[r][2] + gvv[r][3]) * inv + dpr[1];
        float d2 = gvv[r][2] * s_ + (gvv[r][0] + gvv[r][1]) * inv + dpr[2];
        float d3 = gvv[r][3] * s_ + (gvv[r][2] + gvv[r][3]) * inv + dpr[3];
        float iv = sigm(pv[0]), fv = sigm(pv[1]), gg = tanh_(pv[2]), ov = sigm(pv[3]);
        float di = iv * (1.f - iv) * d0;
        float df = fv * (1.f - fv) * d1;
        float dgg = (1.f - gg * gg) * d2;
        float dov = ov * (1.f - ov) * d3;
        float c2 = fv * cr[r] + iv * gg;
        float dc2 = df * cr[r] + fv * dcr[r] + di * gg + iv * dgg;
        float tc = tanh_(c2);
        float h2 = ov * tc;
        float dh2 = dov * tc + ov * (1.f - tc * tc) * dc2;
        cr[r] = c2;
        dcr[r] = dc2;
        out[row * 1024 + j] = h2;
        out[16777216ull + row * 1024 + j] = dh2;
        h_state[((size_t)(p2 * 4 + grp) * 16 + b) * 1024 + j] = f2b(h2);
        dh_state[((size_t)(p2 * 4 + grp) * 16 + b) * 1024 + j] = f2b(dh2);
        float v2 = h2 * h2;
        v2 += __shfl_xor(v2, 1);
        v2 += __shfl_xor(v2, 2);
        v2 += __shfl_xor(v2, 4);
        v2 += __shfl_xor(v2, 8);
        if ((lane & 15) == 0) hpart[((size_t)(p2 * 4 + grp) * 16 + b) * 64 + jt] = v2;
      }
      if (lane == 0)
        __hip_atomic_store(&flags[grp * 64 + jt], t + 1, __ATOMIC_RELEASE,
                           __HIP_MEMORY_SCOPE_AGENT);
    }
  }
}

extern "C" void kernel_launch(void* const* d_in, const int* in_sizes, int n_in,
                              void* d_out, int out_size, void* d_ws, size_t ws_size,
                              hipStream_t stream) {
  const float* x = (const float*)d_in[0];
  const float* g = (const float*)d_in[1];
  const float* wih = (const float*)d_in[2];
  const float* whh = (const float*)d_in[3];
  const float* bih = (const float*)d_in[4];
  const float* bhh = (const float*)d_in[5];
  char* ws = (char*)d_ws;
  int* flags = (int*)(ws + OFF_FLAGS);
  float* hpart = (float*)(ws + OFF_HPART);
  u16* hst = (u16*)(ws + OFF_HST);
  u16* dhst = (u16*)(ws + OFF_DHST);
  float* xn = (float*)(ws + OFF_XNORM);
  float* out = (float*)d_out;

  xnorm_kernel<<<4096, 256, 0, stream>>>(x, xn);
  pregemm_kernel<<<4096, 256, 0, stream>>>(x, wih, bih, bhh, (u16*)d_out);
  hipFuncSetAttribute((const void*)recurrent_kernel,
                      hipFuncAttributeMaxDynamicSharedMemorySize, 149504);
  recurrent_kernel<<<256, 256, 148992, stream>>>(g, whh, xn, hst, dhst, hpart, flags, out);
}

// Round 4
// 2633.700 us; speedup vs baseline: 2.3956x; 2.3956x over previous
//
#include <hip/hip_runtime.h>
#include <hip/hip_bf16.h>

typedef unsigned short u16;
typedef unsigned int u32;
typedef unsigned long long u64;
typedef __attribute__((ext_vector_type(8))) short short8;
typedef __attribute__((ext_vector_type(4))) float floatx4;

#define EPS 0.01f

// ---- workspace layout (bytes) --- total 630784 B ----
#define OFF_FLAGS  (0ull)         // int  [4][64]            1024 B
#define OFF_HPART  (4096ull)      // fp32 [2][4][16][64]     32768 B
#define OFF_HD     (40960ull)     // u32  [2][4][16][1024]   524288 B (lo16=h bf16, hi16=dh bf16)
#define OFF_XNORM  (565248ull)    // fp32 [16384]            65536 B

__device__ __forceinline__ u16 f2b(float v) {
  __hip_bfloat16 b = __float2bfloat16(v);
  return *reinterpret_cast<u16*>(&b);
}
__device__ __forceinline__ float b2f(u16 u) {
  u32 x = ((u32)u) << 16;
  return __uint_as_float(x);
}
__device__ __forceinline__ float halfsel(float w, int hi) {
  u32 u = __float_as_uint(w);
  return b2f((u16)(hi ? (u >> 16) : (u & 0xffffu)));
}
__device__ __forceinline__ float sigm(float x) { return 1.0f / (1.0f + __expf(-x)); }
__device__ __forceinline__ float tanh_(float x) { return 2.0f / (1.0f + __expf(-2.0f * x)) - 1.0f; }

__device__ __forceinline__ u64 ld_sys_u64(const u64* p) {
  return __hip_atomic_load(p, __ATOMIC_RELAXED, __HIP_MEMORY_SCOPE_SYSTEM);
}

// prex chunk addressing (unchanged from round 3): pre-activation for
// (m = t*64+b, col = q*1024 + jt*16 + jj) lives as bf16 inside d_out at fp32 word
// (q>=2 ? 16777216 : 0) + m*1024 + jt*16 + (q&1)*8 + (jj>>1), half = jj&1.
// Byte-disjoint per WG; each chunk is read at step t by the same WG that then
// overwrites those words with final h/dh (same-wave in-order load-before-store).

// ---------------- xnorm2[t*64+b] = sum_k x[t,b,k]^2 ----------------
__global__ void xnorm_kernel(const float* __restrict__ x, float* __restrict__ xn) {
  const int wid = threadIdx.x >> 6, lane = threadIdx.x & 63;
  const int row = blockIdx.x * 4 + wid;
  const float4* p = (const float4*)(x + (size_t)row * 1024);
  float s = 0.f;
  #pragma unroll
  for (int i = 0; i < 4; ++i) {
    float4 v = p[lane + i * 64];
    s += v.x * v.x + v.y * v.y + v.z * v.z + v.w * v.w;
  }
  for (int o = 32; o; o >>= 1) s += __shfl_down(s, o);
  if (lane == 0) xn[row] = s;
}

// ------- prex = x @ W_ih^T + (b_ih+b_hh), fp32 in, bf16 chunks into d_out -------
#define LDA 88
__global__ __launch_bounds__(256) void pregemm_kernel(const float* __restrict__ A,
                                                      const float* __restrict__ Bw,
                                                      const float* __restrict__ bih,
                                                      const float* __restrict__ bhh,
                                                      u16* __restrict__ O) {
  __shared__ u16 Al[128 * LDA];
  __shared__ u16 Bl[128 * LDA];
  const int tid = threadIdx.x, lane = tid & 63, wid = tid >> 6;
  const int bm = blockIdx.x & 127, bn = blockIdx.x >> 7;
  const size_t m0 = (size_t)bm * 128, n0 = (size_t)bn * 128;
  const int wrow = (wid & 1) * 64, wcol = (wid >> 1) * 64;
  const int lrow = lane & 15, lko = (lane >> 4) * 8;
  floatx4 acc[4][4];
  #pragma unroll
  for (int i = 0; i < 4; ++i)
    #pragma unroll
    for (int j = 0; j < 4; ++j) acc[i][j] = (floatx4)(0.0f);

  for (int k0 = 0; k0 < 1024; k0 += 64) {
    __syncthreads();
    #pragma unroll
    for (int i = 0; i < 8; ++i) {
      int cid = tid + i * 256;
      int row = cid >> 4;
      int kc = cid & 15;
      float4 va = *(const float4*)&A[(m0 + row) * 1024 + k0 + kc * 4];
      ushort4 oa;
      oa.x = f2b(va.x); oa.y = f2b(va.y); oa.z = f2b(va.z); oa.w = f2b(va.w);
      *(ushort4*)&Al[row * LDA + kc * 4] = oa;
      float4 vb = *(const float4*)&Bw[(n0 + row) * 1024 + k0 + kc * 4];
      ushort4 ob;
      ob.x = f2b(vb.x); ob.y = f2b(vb.y); ob.z = f2b(vb.z); ob.w = f2b(vb.w);
      *(ushort4*)&Bl[row * LDA + kc * 4] = ob;
    }
    __syncthreads();
    #pragma unroll
    for (int ks = 0; ks < 2; ++ks) {
      short8 af[4], bf[4];
      #pragma unroll
      for (int i = 0; i < 4; ++i)
        af[i] = *(const short8*)&Al[(wrow + i * 16 + lrow) * LDA + ks * 32 + lko];
      #pragma unroll
      for (int j = 0; j < 4; ++j)
        bf[j] = *(const short8*)&Bl[(wcol + j * 16 + lrow) * LDA + ks * 32 + lko];
      #pragma unroll
      for (int i = 0; i < 4; ++i)
        #pragma unroll
        for (int j = 0; j < 4; ++j)
          acc[i][j] = __builtin_amdgcn_mfma_f32_16x16x32_bf16(af[i], bf[j], acc[i][j], 0, 0, 0);
    }
  }
  #pragma unroll
  for (int j = 0; j < 4; ++j) {
    const size_t col = n0 + wcol + j * 16 + lrow;
    const float bv = bih[col] + bhh[col];
    const size_t q = col >> 10;
    const size_t jt = (col & 1023) >> 4;
    const size_t jj = col & 15;
    const size_t cbase = ((q >= 2) ? 33554432ull : 0ull) + jt * 32 + (q & 1) * 16 + jj;
    #pragma unroll
    for (int i = 0; i < 4; ++i) {
      const size_t rowb = m0 + wrow + i * 16 + (lane >> 4) * 4;
      #pragma unroll
      for (int r = 0; r < 4; ++r) O[cbase + (rowb + r) * 2048] = f2b(acc[i][j][r] + bv);
    }
  }
}

// ---------------- persistent recurrent kernel v2 (fence-free) ----------------
// 256 WGs x 256 thr, 1 WG/CU. grp=blk&3 owns 16 batch rows; jt=blk>>2 owns 16
// j-cols x 4 gates. W_hh slice LDS-resident (132096 B). All cross-WG data
// (hd/hpart/flags) via relaxed SYSTEM-scope atomics (sc0/sc1 -> coherent at IF$,
// no wbl2/inv fences ever). Wave w owns accumulator element r=w -> epilogue
// parallel across 4 waves. A-fragments loaded directly from global (no Ast LDS,
// no mid-GEMM barriers). 2 barriers/step total.
__global__ __launch_bounds__(256, 1) void recurrent_kernel(
    const float* __restrict__ gin, const float* __restrict__ whh,
    const float* __restrict__ xnorm2, u32* hd, float* hpart, int* flags, float* out) {
  extern __shared__ char smem[];
  u16* Wlds = (u16*)smem;                   // [64][1032]  132096 B
  float* rbuf = (float*)(smem + 132096);    // [2][4][4][3][64] fp32 = 24576 B

  const int tid = threadIdx.x, lane = tid & 63, wid = tid >> 6;
  const int grp = blockIdx.x & 3, jt = blockIdx.x >> 2;
  const int lrow = lane & 15, hv = lane >> 4, lko = hv * 8;
  const int j = jt * 16 + lrow;     // this lane's output column
  const int bloc = hv * 4 + wid;    // this lane's local batch row (0..15)

  // W_hh slice: LDS row q*16+jj <- global row q*1024 + jt*16 + jj (fp32 -> bf16)
  #pragma unroll
  for (int it = 0; it < 64; ++it) {
    int cid = tid + it * 256;
    int rowl = cid >> 8;
    int kc = cid & 255;
    int q = rowl >> 4, jj = rowl & 15;
    size_t grow = (size_t)q * 1024 + (size_t)jt * 16 + jj;
    float4 v = *(const float4*)&whh[grow * 1024 + kc * 4];
    ushort4 o;
    o.x = f2b(v.x); o.y = f2b(v.y); o.z = f2b(v.z); o.w = f2b(v.w);
    *(ushort4*)&Wlds[rowl * 1032 + kc * 4] = o;
  }
  __syncthreads();

  float cr = 0.f, dcr = 0.f;

  for (int t = 0; t < 256; ++t) {
    const int p = t & 1, p2 = p ^ 1;
    const size_t m = (size_t)t * 64 + grp * 16 + bloc;

    // ---- prefetch (producer-independent data) BEFORE the poll ----
    float gv[4];
    #pragma unroll
    for (int q = 0; q < 4; ++q) gv[q] = EPS * gin[m * 4096 + (size_t)q * 1024 + j];
    const size_t fb = m * 1024 + (size_t)jt * 16 + (lrow >> 1);
    float pw0 = out[fb];
    float pw1 = out[fb + 8];
    float pw2 = out[16777216ull + fb];
    float pw3 = out[16777216ull + fb + 8];
    float xnv = xnorm2[m];
    asm volatile("" ::: "memory");  // pin prefetch issue before the poll

    floatx4 acc[2][4];
    #pragma unroll
    for (int m2 = 0; m2 < 2; ++m2)
      #pragma unroll
      for (int q = 0; q < 4; ++q) acc[m2][q] = (floatx4)(0.0f);

    float hn = 0.f;
    if (t > 0) {
      // ---- all waves poll all 64 producer flags of this grp (own jt exempt) ----
      for (int it = 0; it < 4000000; ++it) {
        int v = __hip_atomic_load(&flags[grp * 64 + lane], __ATOMIC_RELAXED,
                                  __HIP_MEMORY_SCOPE_SYSTEM);
        if (lane == jt) v = 0x7fffffff;
        if (__all(v >= t)) break;
        __builtin_amdgcn_s_sleep(1);
      }
      asm volatile("" ::: "memory");

      // ---- |h|^2 for this lane's b: 64 jt-partials, 4/lane + xor-reduce ----
      {
        const u64* hp = (const u64*)(hpart + ((size_t)(p * 4 + grp) * 16 + bloc) * 64 + lrow * 4);
        u64 q0 = ld_sys_u64(hp), q1 = ld_sys_u64(hp + 1);
        float s = __uint_as_float((u32)q0) + __uint_as_float((u32)(q0 >> 32)) +
                  __uint_as_float((u32)q1) + __uint_as_float((u32)(q1 >> 32));
        s += __shfl_xor(s, 1);
        s += __shfl_xor(s, 2);
        s += __shfl_xor(s, 4);
        s += __shfl_xor(s, 8);
        hn = s;
      }

      // ---- GEMM: wave wid owns K quarter [wid*256, wid*256+256) ----
      // A-fragments direct from hd (u32 = h|dh<<16): lane reads row lrow,
      // k = k0 + hv*8 + 0..7 -> 4 x u64 sc-atomic loads (64B/row segments).
      const u32* hdrow = hd + ((size_t)(p * 4 + grp)) * 16384 + (size_t)lrow * 1024;
      const int kb = wid * 256 + lko;
      u64 A0 = ld_sys_u64((const u64*)(hdrow + kb));
      u64 A1 = ld_sys_u64((const u64*)(hdrow + kb + 2));
      u64 A2 = ld_sys_u64((const u64*)(hdrow + kb + 4));
      u64 A3 = ld_sys_u64((const u64*)(hdrow + kb + 6));
      #pragma unroll
      for (int ks = 0; ks < 8; ++ks) {
        u64 N0 = A0, N1 = A1, N2 = A2, N3 = A3;
        if (ks < 7) {
          const int nb = kb + (ks + 1) * 32;
          N0 = ld_sys_u64((const u64*)(hdrow + nb));
          N1 = ld_sys_u64((const u64*)(hdrow + nb + 2));
          N2 = ld_sys_u64((const u64*)(hdrow + nb + 4));
          N3 = ld_sys_u64((const u64*)(hdrow + nb + 6));
        }
        u32 w[8] = {(u32)A0, (u32)(A0 >> 32), (u32)A1, (u32)(A1 >> 32),
                    (u32)A2, (u32)(A2 >> 32), (u32)A3, (u32)(A3 >> 32)};
        short8 a0, a1;
        #pragma unroll
        for (int i = 0; i < 8; ++i) {
          a0[i] = (short)(w[i] & 0xffffu);
          a1[i] = (short)(w[i] >> 16);
        }
        const int k0 = wid * 256 + ks * 32;
        #pragma unroll
        for (int q = 0; q < 4; ++q) {
          short8 bq = *(const short8*)&Wlds[(q * 16 + lrow) * 1032 + k0 + lko];
          acc[0][q] = __builtin_amdgcn_mfma_f32_16x16x32_bf16(a0, bq, acc[0][q], 0, 0, 0);
          acc[1][q] = __builtin_amdgcn_mfma_f32_16x16x32_bf16(a1, bq, acc[1][q], 0, 0, 0);
        }
        A0 = N0; A1 = N1; A2 = N2; A3 = N3;
      }
    }

    // ---- cross-wave K reduction: wave w keeps element r=w, exchanges the rest ----
    float fin[2][4] = {{0.f, 0.f, 0.f, 0.f}, {0.f, 0.f, 0.f, 0.f}};
    if (t > 0) {
      __syncthreads();  // all GEMMs done (rbuf WAR covered by end-of-step barrier)
      #pragma unroll
      for (int m2 = 0; m2 < 2; ++m2)
        #pragma unroll
        for (int q = 0; q < 4; ++q)
          #pragma unroll
          for (int s2 = 0; s2 < 3; ++s2) {
            int r = s2 + (s2 >= wid ? 1 : 0);
            rbuf[((((m2 * 4 + q) * 4 + wid) * 3 + s2) << 6) + lane] = acc[m2][q][r];
          }
      __syncthreads();
      #pragma unroll
      for (int m2 = 0; m2 < 2; ++m2)
        #pragma unroll
        for (int q = 0; q < 4; ++q) {
          float sfin = acc[m2][q][wid];
          #pragma unroll
          for (int w2 = 0; w2 < 4; ++w2)
            if (w2 != wid) {
              int slot = wid - (wid > w2 ? 1 : 0);
              sfin += rbuf[((((m2 * 4 + q) * 4 + w2) * 3 + slot) << 6) + lane];
            }
          fin[m2][q] = sfin;
        }
    }

    // ---- epilogue: one cell (bloc, j) per lane ----
    {
      const int hi = lrow & 1;
      float pre0 = halfsel(pw0, hi), pre1 = halfsel(pw1, hi);
      float pre2 = halfsel(pw2, hi), pre3 = halfsel(pw3, hi);
      float sum2 = xnv + hn;
      float nrm = sqrtf(sum2 + 2.0f);
      float inv = 1.0f / nrm;
      float s_ = sum2 * inv;
      float pv0 = fin[0][0] + pre0, pv1 = fin[0][1] + pre1;
      float pv2 = fin[0][2] + pre2, pv3 = fin[0][3] + pre3;
      float d0 = gv[0] * (s_ + inv) + gv[1] * inv + fin[1][0];
      float d1 = gv[1] * s_ + (gv[2] + gv[3]) * inv + fin[1][1];
      float d2 = gv[2] * s_ + (gv[0] + gv[1]) * inv + fin[1][2];
      float d3 = gv[3] * s_ + (gv[2] + gv[3]) * inv + fin[1][3];
      float iv = sigm(pv0), fv = sigm(pv1), gg = tanh_(pv2), ov = sigm(pv3);
      float di = iv * (1.f - iv) * d0;
      float df = fv * (1.f - fv) * d1;
      float dgg = (1.f - gg * gg) * d2;
      float dov = ov * (1.f - ov) * d3;
      float c2 = fv * cr + iv * gg;
      float dc2 = df * cr + fv * dcr + di * gg + iv * dgg;
      float tc = tanh_(c2);
      float h2 = ov * tc;
      float dh2 = dov * tc + ov * (1.f - tc * tc) * dc2;
      cr = c2;
      dcr = dc2;
      out[m * 1024 + j] = h2;
      out[16777216ull + m * 1024 + j] = dh2;
      u32 packv = (u32)f2b(h2) | ((u32)f2b(dh2) << 16);
      __hip_atomic_store(&hd[((size_t)(p2 * 4 + grp)) * 16384 + (size_t)bloc * 1024 + j],
                         packv, __ATOMIC_RELAXED, __HIP_MEMORY_SCOPE_SYSTEM);
      float v2 = h2 * h2;
      v2 += __shfl_xor(v2, 1);
      v2 += __shfl_xor(v2, 2);
      v2 += __shfl_xor(v2, 4);
      v2 += __shfl_xor(v2, 8);
      if (lrow == 0)
        __hip_atomic_store(&hpart[((size_t)(p2 * 4 + grp) * 16 + bloc) * 64 + jt],
                           v2, __ATOMIC_RELAXED, __HIP_MEMORY_SCOPE_SYSTEM);
    }
    __syncthreads();  // drains vmcnt for ALL waves' state stores (m97-documented)
    if (tid == 0)
      __hip_atomic_store(&flags[grp * 64 + jt], t + 1, __ATOMIC_RELAXED,
                         __HIP_MEMORY_SCOPE_SYSTEM);
  }
}

extern "C" void kernel_launch(void* const* d_in, const int* in_sizes, int n_in,
                              void* d_out, int out_size, void* d_ws, size_t ws_size,
                              hipStream_t stream) {
  const float* x = (const float*)d_in[0];
  const float* g = (const float*)d_in[1];
  const float* wih = (const float*)d_in[2];
  const float* whh = (const float*)d_in[3];
  const float* bih = (const float*)d_in[4];
  const float* bhh = (const float*)d_in[5];
  char* ws = (char*)d_ws;
  int* flags = (int*)(ws + OFF_FLAGS);
  float* hpart = (float*)(ws + OFF_HPART);
  u32* hd = (u32*)(ws + OFF_HD);
  float* xn = (float*)(ws + OFF_XNORM);
  float* out = (float*)d_out;

  xnorm_kernel<<<4096, 256, 0, stream>>>(x, xn);
  pregemm_kernel<<<4096, 256, 0, stream>>>(x, wih, bih, bhh, (u16*)d_out);
  hipFuncSetAttribute((const void*)recurrent_kernel,
                      hipFuncAttributeMaxDynamicSharedMemorySize, 156672);
  recurrent_kernel<<<256, 256, 156672, stream>>>(g, whh, xn, hd, hpart, flags, out);
}